// Round 7
// baseline (482.599 us; speedup 1.0000x reference)
//
#include <hip/hip_runtime.h>
#include <hip/hip_bf16.h>
#include <stdint.h>

#define HWSZ 16384
#define CCH 192
#define NB 8
#define NHEAD 4
#define DHEAD 48

typedef unsigned short u16;
typedef __bf16 bf16x8 __attribute__((ext_vector_type(8)));
typedef float f32x4 __attribute__((ext_vector_type(4)));
typedef short s16x8 __attribute__((ext_vector_type(8)));
typedef short s16x4 __attribute__((ext_vector_type(4)));

__device__ __forceinline__ float b2f(u16 h){
  union { unsigned u; float f; } v; v.u = ((unsigned)h) << 16; return v.f;
}
__device__ __forceinline__ u16 f2b(float f){
  union { float f; unsigned u; } v; v.f = f;
  unsigned r = v.u + 0x7fffu + ((v.u >> 16) & 1u);
  return (u16)(r >> 16);
}

// ---------------------------------------------------------------------------
// K0: fold LN gamma into weights: W'[o,c] = bf16(W[o,c]*g[c]); row sums
// a[o] = sum_c b2f(W'), d[o] = sum_c W[o,c]*b[c] (f32).  ad: [3][2][192].
// ---------------------------------------------------------------------------
__global__ __launch_bounds__(256) void k_wpack(
    const float* __restrict__ wq, const float* __restrict__ wk,
    const float* __restrict__ wv,
    const float* __restrict__ lnw, const float* __restrict__ lnb,
    u16* __restrict__ o, float* __restrict__ ad)
{
  int m = blockIdx.x;
  const float* src = (m == 0) ? wq : (m == 1) ? wk : wv;
  u16* dst = o + (size_t)m * CCH * CCH;
  int t = threadIdx.x;
  if (t < CCH){
    const float* row = src + (size_t)t * CCH;
    float a = 0.f, d = 0.f;
    for (int c = 0; c < CCH; c += 4){
      float4 w = *(const float4*)(row + c);
      float4 g = *(const float4*)(lnw + c);
      float4 bb = *(const float4*)(lnb + c);
      u16 p0 = f2b(w.x * g.x), p1 = f2b(w.y * g.y);
      u16 p2 = f2b(w.z * g.z), p3 = f2b(w.w * g.w);
      a += b2f(p0) + b2f(p1) + b2f(p2) + b2f(p3);
      d += w.x * bb.x + w.y * bb.y + w.z * bb.z + w.w * bb.w;
      s16x4 pk;
      pk[0] = (short)p0; pk[1] = (short)p1; pk[2] = (short)p2; pk[3] = (short)p3;
      *(s16x4*)(dst + (size_t)t * CCH + c) = pk;
    }
    ad[(m * 2 + 0) * CCH + t] = a;
    ad[(m * 2 + 1) * CCH + t] = d;
  }
}

// ---------------------------------------------------------------------------
// KC: fused LN-folded conv1x1 GEMM. 256 thr, 64 px. Phase A: stage RAW x as
// bf16 into tr-read subtiled LDS + per-px partial stats (shfl-reduced to 2KB).
// Barrier. Wave0 finalizes mu/rs WHILE all waves run GEMM kb-loop. Barrier.
// Epilogue: out = rs*(acc - mu*a[o]) + d[o].  z=0: xx->{k,v}; z=1: q_in->q.
// ---------------------------------------------------------------------------
__global__ __launch_bounds__(256, 4) void k_convf(
    const float* __restrict__ xx, const float* __restrict__ q_in,
    const u16* __restrict__ Wb, const float* __restrict__ ad,
    u16* __restrict__ Ok, u16* __restrict__ Ov, u16* __restrict__ Oq)
{
  __shared__ u16 lnT[48 * 264];     // 25344 B subtiled bf16 tile
  __shared__ float2 redf[4][64];    // 2 KB wave-level {s,ss} per px
  __shared__ float2 mures[64];      // {mu, rstd} per px
  int tid = threadIdx.x;
  int b = blockIdx.y, z = blockIdx.z;
  int p0 = blockIdx.x * 64;
  int grp = tid & 7;                // 8-px group
  int cs  = tid >> 3;               // channel slot 0..31
  int lane = tid & 63, w = tid >> 6;

  const float* xb = (z ? q_in : xx) + (size_t)b * CCH * HWSZ + p0 + grp * 8;

  // Phase A: 12 independent float4 loads (6 channels x 8 px)
  float4 v[12];
  #pragma unroll
  for (int i = 0; i < 6; ++i){
    v[2 * i]     = *(const float4*)(xb + (size_t)(i * 32 + cs) * HWSZ);
    v[2 * i + 1] = *(const float4*)(xb + (size_t)(i * 32 + cs) * HWSZ + 4);
  }
  // partial stats (per px j over this thread's 6 channels)
  float s[8] = {}, ss[8] = {};
  #pragma unroll
  for (int i = 0; i < 6; ++i){
    float e0 = v[2*i].x, e1 = v[2*i].y, e2 = v[2*i].z, e3 = v[2*i].w;
    float e4 = v[2*i+1].x, e5 = v[2*i+1].y, e6 = v[2*i+1].z, e7 = v[2*i+1].w;
    s[0] += e0; ss[0] += e0*e0;  s[1] += e1; ss[1] += e1*e1;
    s[2] += e2; ss[2] += e2*e2;  s[3] += e3; ss[3] += e3*e3;
    s[4] += e4; ss[4] += e4*e4;  s[5] += e5; ss[5] += e5*e5;
    s[6] += e6; ss[6] += e6*e6;  s[7] += e7; ss[7] += e7*e7;
  }
  // stage bf16 subtiled (kb = i, kr = cs)
  #pragma unroll
  for (int i = 0; i < 6; ++i){
    s16x8 pk;
    pk[0] = (short)f2b(v[2*i].x);   pk[1] = (short)f2b(v[2*i].y);
    pk[2] = (short)f2b(v[2*i].z);   pk[3] = (short)f2b(v[2*i].w);
    pk[4] = (short)f2b(v[2*i+1].x); pk[5] = (short)f2b(v[2*i+1].y);
    pk[6] = (short)f2b(v[2*i+1].z); pk[7] = (short)f2b(v[2*i+1].w);
    int tile = (cs >> 2) & 1;
    int mr   = ((cs >> 3) << 2) | (cs & 3);
    int ti   = (i * 4 + (grp >> 1)) * 2 + tile;
    *(s16x8*)(&lnT[ti * 264 + mr * 16 + (grp & 1) * 8]) = pk;
  }
  // shfl-reduce stats across the wave's 8 channel slots (lanes l, l^8, l^16, l^32)
  #pragma unroll
  for (int m = 8; m <= 32; m <<= 1){
    #pragma unroll
    for (int j = 0; j < 8; ++j){
      s[j]  += __shfl_xor(s[j],  m);
      ss[j] += __shfl_xor(ss[j], m);
    }
  }
  if (lane < 8){
    #pragma unroll
    for (int j = 0; j < 8; ++j)
      redf[w][lane * 8 + j] = make_float2(s[j], ss[j]);
  }
  __syncthreads();

  // Wave 0: finalize per-px stats (overlaps with other waves' GEMM below)
  if (tid < 64){
    float2 t0 = redf[0][tid], t1 = redf[1][tid];
    float2 t2 = redf[2][tid], t3 = redf[3][tid];
    float s_ = t0.x + t1.x + t2.x + t3.x;
    float q_ = t0.y + t1.y + t2.y + t3.y;
    float mu = s_ * (1.f / CCH);
    float var = q_ * (1.f / CCH) - mu * mu;
    mures[tid] = make_float2(mu, rsqrtf(var + 1e-5f));
  }

  // GEMM phase: 4 waves, wave = M-quarter. z=0: t=0 -> k (mat1), t=1 -> v (mat2).
  int quad = lane >> 4, r = lane & 15;
  int wm = w * 48;
  int nt = z ? 1 : 2;
  size_t ob = (size_t)b * CCH * HWSZ;
  unsigned lvb0 = (unsigned)(uintptr_t)(&lnT[0]) + 2u * (unsigned)(r + quad * 64);

  for (int t = 0; t < nt; ++t){
    int mi = z ? 0 : (t + 1);
    const u16* A0 = Wb + (size_t)mi * CCH * CCH + (size_t)wm * CCH;
    const float* aA = ad + (mi * 2 + 0) * CCH;
    const float* dA = ad + (mi * 2 + 1) * CCH;
    u16* O = z ? Oq : (t ? Ov : Ok);
    f32x4 acc[3][4] = {};
    bf16x8 aC[3], aN[3];
    #pragma unroll
    for (int i = 0; i < 3; ++i)
      aC[i] = *(const bf16x8*)(A0 + (size_t)(i * 16 + r) * CCH + quad * 8);
    #pragma unroll
    for (int kb = 0; kb < 6; ++kb){
      s16x4 lo[4], hi[4];
      #pragma unroll
      for (int j = 0; j < 4; ++j){
        unsigned a = lvb0 + (unsigned)(kb * 4224 + j * 1056);
        asm volatile("ds_read_b64_tr_b16 %0, %1" : "=&v"(lo[j]) : "v"(a));
        asm volatile("ds_read_b64_tr_b16 %0, %1 offset:528" : "=&v"(hi[j]) : "v"(a));
      }
      if (kb < 5){
        #pragma unroll
        for (int i = 0; i < 3; ++i)
          aN[i] = *(const bf16x8*)(A0 + (size_t)(i * 16 + r) * CCH + (kb + 1) * 32 + quad * 8);
      }
      asm volatile("s_waitcnt lgkmcnt(0)" ::: "memory");
      __builtin_amdgcn_sched_barrier(0);
      #pragma unroll
      for (int j = 0; j < 4; ++j){
        union { s16x8 s; bf16x8 b; } u;
        u.s = __builtin_shufflevector(lo[j], hi[j], 0, 1, 2, 3, 4, 5, 6, 7);
        #pragma unroll
        for (int i = 0; i < 3; ++i)
          acc[i][j] = __builtin_amdgcn_mfma_f32_16x16x32_bf16(aC[i], u.b, acc[i][j], 0, 0, 0);
      }
      #pragma unroll
      for (int i = 0; i < 3; ++i) aC[i] = aN[i];
    }
    if (t == 0) __syncthreads();     // mures ready (wave0 finalize done)
    // Epilogue: LN correction + store
    #pragma unroll
    for (int j = 0; j < 4; ++j){
      int px = j * 16 + r;
      float2 mr_ = mures[px];
      #pragma unroll
      for (int i = 0; i < 3; ++i){
        #pragma unroll
        for (int rg = 0; rg < 4; ++rg){
          int o = wm + i * 16 + quad * 4 + rg;
          float val = mr_.y * (acc[i][j][rg] - mr_.x * aA[o]) + dA[o];
          O[ob + (size_t)o * HWSZ + p0 + px] = f2b(val);
        }
      }
    }
  }
}

// ---------------------------------------------------------------------------
// K3: depthwise 3x3, register-rolling (no LDS). Thread = 8x8 px patch;
// 10 row loads up front (ILP), one __syncthreads (vmcnt drain) for in-place
// safety, halo via __shfl.
// ---------------------------------------------------------------------------
__global__ __launch_bounds__(256) void k_dw3(
    const float* __restrict__ wq, const float* __restrict__ wk,
    const float* __restrict__ wv,
    u16* __restrict__ bq, u16* __restrict__ bk, u16* __restrict__ bv,
    float* __restrict__ ssq_q, float* __restrict__ ssq_k)
{
  int tid = threadIdx.x;
  int bc  = blockIdx.x;                 // b*192 + c
  int z   = blockIdx.y;                 // 0=q 1=k 2=v
  int c   = bc % CCH;
  const float* wd = (z == 0) ? wq : (z == 1) ? wk : wv;
  u16* buf = (z == 0) ? bq : (z == 1) ? bk : bv;
  float w[9];
  #pragma unroll
  for (int t = 0; t < 9; ++t) w[t] = wd[c * 9 + t];
  u16* p = buf + (size_t)bc * HWSZ;

  int xseg = tid & 15, ygrp = tid >> 4;
  int x0 = xseg * 8, y0 = ygrp * 8;

  s16x8 zz = {0,0,0,0,0,0,0,0};
  s16x8 raw[10];
  #pragma unroll
  for (int rr = 0; rr < 10; ++rr){
    int yy = y0 - 1 + rr;
    raw[rr] = (yy >= 0 && yy < 128) ? *(const s16x8*)(p + yy * 128 + x0) : zz;
  }
  __syncthreads();

  float cf[10][8];
  float lf[10], rgt[10];
  #pragma unroll
  for (int rr = 0; rr < 10; ++rr){
    #pragma unroll
    for (int j = 0; j < 8; ++j) cf[rr][j] = b2f((u16)raw[rr][j]);
    float l  = __shfl_up(cf[rr][7], 1);
    float rr_ = __shfl_down(cf[rr][0], 1);
    lf[rr]  = (xseg > 0)  ? l   : 0.f;
    rgt[rr] = (xseg < 15) ? rr_ : 0.f;
  }

  float ss = 0.f;
  #pragma unroll
  for (int k = 0; k < 8; ++k){
    float acc[8] = {0.f,0.f,0.f,0.f,0.f,0.f,0.f,0.f};
    #pragma unroll
    for (int dy = 0; dy < 3; ++dy){
      int rr = k + dy;
      float wl = w[dy * 3], wc = w[dy * 3 + 1], wr = w[dy * 3 + 2];
      acc[0] += wl * lf[rr] + wc * cf[rr][0] + wr * cf[rr][1];
      #pragma unroll
      for (int j = 1; j < 7; ++j)
        acc[j] += wl * cf[rr][j - 1] + wc * cf[rr][j] + wr * cf[rr][j + 1];
      acc[7] += wl * cf[rr][6] + wc * cf[rr][7] + wr * rgt[rr];
    }
    s16x8 pk;
    #pragma unroll
    for (int j = 0; j < 8; ++j){
      pk[j] = (short)f2b(acc[j]);
      ss += acc[j] * acc[j];
    }
    *(s16x8*)(p + (y0 + k) * 128 + x0) = pk;
  }

  if (z < 2){
    #pragma unroll
    for (int m = 32; m > 0; m >>= 1) ss += __shfl_xor(ss, m);
    if ((tid & 63) == 0) atomicAdd(&((z == 0) ? ssq_q : ssq_k)[bc], ss);
  }
}

// ---------------------------------------------------------------------------
// K4: raw gram G[b][h][c][d] += sum_n q[c,n]*k[d,n], split-K (16 chunks),
// MFMA fragments straight from global; 4-wave LDS reduce then atomicAdd.
// ---------------------------------------------------------------------------
__global__ void k_gram(const u16* __restrict__ q, const u16* __restrict__ k,
                       float* __restrict__ G)
{
  __shared__ float gs[4 * 48 * 49];     // padded rows (49) to spread banks
  int tid = threadIdx.x;
  int chunk = blockIdx.x;
  int h = blockIdx.y, b = blockIdx.z;
  int lane = tid & 63, w = tid >> 6;
  int quad = lane >> 4, r = lane & 15;
  int nb = chunk * 1024 + w * 256;
  const u16* qb = q + ((size_t)b * CCH + h * DHEAD) * HWSZ;
  const u16* kb = k + ((size_t)b * CCH + h * DHEAD) * HWSZ;
  f32x4 acc[3][3] = {};
  for (int s = 0; s < 8; ++s){
    int kk = nb + s * 32 + quad * 8;
    bf16x8 af[3], bfr[3];
    #pragma unroll
    for (int i = 0; i < 3; ++i){
      af[i]  = *(const bf16x8*)(qb + (size_t)(i * 16 + r) * HWSZ + kk);
      bfr[i] = *(const bf16x8*)(kb + (size_t)(i * 16 + r) * HWSZ + kk);
    }
    #pragma unroll
    for (int i = 0; i < 3; ++i)
      #pragma unroll
      for (int j = 0; j < 3; ++j)
        acc[i][j] = __builtin_amdgcn_mfma_f32_16x16x32_bf16(af[i], bfr[j], acc[i][j], 0, 0, 0);
  }
  float* gw = gs + w * (48 * 49);
  #pragma unroll
  for (int i = 0; i < 3; ++i)
    #pragma unroll
    for (int j = 0; j < 3; ++j)
      #pragma unroll
      for (int rg = 0; rg < 4; ++rg){
        int row = i * 16 + quad * 4 + rg;
        int col = j * 16 + r;
        gw[row * 49 + col] = acc[i][j][rg];
      }
  __syncthreads();
  float* gb = G + (size_t)(b * NHEAD + h) * (DHEAD * DHEAD);
  #pragma unroll
  for (int t = 0; t < 9; ++t){
    int e = t * 256 + tid;              // 0..2303
    int row = e / 48, col = e - row * 48;
    int o = row * 49 + col;
    float s = gs[o] + gs[48 * 49 + o] + gs[2 * 48 * 49 + o] + gs[3 * 48 * 49 + o];
    atomicAdd(&gb[e], s);
  }
}

// ---------------------------------------------------------------------------
// K5: per (b,h) build M-slice = Wp[:, h*48:+48] @ P_h  (192x48, bf16)
// where P_h = softmax(G * rq*rk*temp). M is the fused (proj @ blockdiag(P)).
// ---------------------------------------------------------------------------
__global__ __launch_bounds__(256) void k_mk(
    const float* __restrict__ G, const float* __restrict__ ssq_q,
    const float* __restrict__ ssq_k, const float* __restrict__ temp,
    const float* __restrict__ wp, u16* __restrict__ Mout)
{
  __shared__ u16 Pt[48 * 72];     // P^T rows d, cols c (pad 48->72, zeros)
  __shared__ u16 wA[192 * 72];    // Wp head-slice rows o, cols c (pad zeros)
  __shared__ float rks[48];
  int tid = threadIdx.x;
  int h = blockIdx.x, b = blockIdx.y;
  {
    s16x8 z = {};
    #pragma unroll
    for (int i = 0; i < 2; ++i){
      int idx = (i * 256 + tid) * 8;
      if (idx < 48 * 72) *(s16x8*)(&Pt[idx]) = z;
    }
    #pragma unroll
    for (int i = 0; i < 7; ++i){
      int idx = (i * 256 + tid) * 8;
      if (idx < 192 * 72) *(s16x8*)(&wA[idx]) = z;
    }
  }
  if (tid < DHEAD)
    rks[tid] = 1.f / fmaxf(sqrtf(ssq_k[b * CCH + h * DHEAD + tid]), 1e-12f);
  __syncthreads();
  if (tid < DHEAD){
    float rq = temp[h] / fmaxf(sqrtf(ssq_q[b * CCH + h * DHEAD + tid]), 1e-12f);
    const float* gr = G + (size_t)(b * NHEAD + h) * (DHEAD * DHEAD) + tid * DHEAD;
    float a[DHEAD];
    float mx = -1e30f;
    #pragma unroll
    for (int d = 0; d < DHEAD; ++d){
      a[d] = gr[d] * rq * rks[d];
      mx = fmaxf(mx, a[d]);
    }
    float sum = 0.f;
    #pragma unroll
    for (int d = 0; d < DHEAD; ++d){ a[d] = __expf(a[d] - mx); sum += a[d]; }
    float inv = 1.f / sum;
    #pragma unroll
    for (int d = 0; d < DHEAD; ++d) Pt[d * 72 + tid] = f2b(a[d] * inv);
  }
  {
    const float* wb = wp + h * DHEAD;
    #pragma unroll
    for (int i = 0; i < 9; ++i){
      int e = (i * 256 + tid) * 4;       // 9216 = 192*48
      int row = e / DHEAD, col = e - row * DHEAD;
      float4 v = *(const float4*)(wb + (size_t)row * CCH + col);
      s16x4 pk;
      pk[0] = (short)f2b(v.x); pk[1] = (short)f2b(v.y);
      pk[2] = (short)f2b(v.z); pk[3] = (short)f2b(v.w);
      *(s16x4*)(&wA[row * 72 + col]) = pk;
    }
  }
  __syncthreads();
  int lane = tid & 63, wid = tid >> 6;
  int quad = lane >> 4, r = lane & 15;
  int wm = wid * 48;
  f32x4 acc[3][3] = {};
  #pragma unroll
  for (int ks = 0; ks < 2; ++ks){
    int k0 = ks * 32;
    bf16x8 af[3], bf[3];
    #pragma unroll
    for (int i = 0; i < 3; ++i)
      af[i] = *(const bf16x8*)(&wA[(wm + i * 16 + r) * 72 + k0 + quad * 8]);
    #pragma unroll
    for (int j = 0; j < 3; ++j)
      bf[j] = *(const bf16x8*)(&Pt[(j * 16 + r) * 72 + k0 + quad * 8]);
    #pragma unroll
    for (int i = 0; i < 3; ++i)
      #pragma unroll
      for (int j = 0; j < 3; ++j)
        acc[i][j] = __builtin_amdgcn_mfma_f32_16x16x32_bf16(af[i], bf[j], acc[i][j], 0, 0, 0);
  }
  u16* mb = Mout + (size_t)b * (CCH * CCH) + h * DHEAD;
  #pragma unroll
  for (int i = 0; i < 3; ++i)
    #pragma unroll
    for (int j = 0; j < 3; ++j)
      #pragma unroll
      for (int rg = 0; rg < 4; ++rg){
        int o = wm + i * 16 + quad * 4 + rg;
        int d = j * 16 + r;
        mb[(size_t)o * CCH + d] = f2b(acc[i][j][rg]);
      }
}

// ---------------------------------------------------------------------------
// K6: fused attention+proj GEMM  Out[b][o][n] = sum_c M[b][o][c]*V[b][c][n]
// + resid.  B-fragments via ds_read_b64_tr_b16 from 16x16-subtiled LDS.
// ---------------------------------------------------------------------------
__global__ __launch_bounds__(256) void k_gemmv(
    const u16* __restrict__ M, const u16* __restrict__ V,
    float* __restrict__ Out, const float* __restrict__ resid)
{
  __shared__ u16 lA[64 * 200];     // M slice rows
  __shared__ u16 lV[96 * 264];     // 6kb x 8nb x 2 tiles of 16x16 (+8 pad)
  int tid = threadIdx.x;
  int n0 = blockIdx.x * 128;
  int m0 = blockIdx.y * 64;
  int b  = blockIdx.z;
  {
    const u16* ap = M + (size_t)b * (CCH * CCH) + m0 * CCH;
    #pragma unroll
    for (int i = 0; i < 6; ++i){
      int off = (i * 256 + tid) * 8;
      int row = off / CCH, col = off - row * CCH;
      *(int4*)(&lA[row * 200 + col]) = *(const int4*)(ap + off);
    }
  }
  {
    const u16* vp = V + (size_t)b * CCH * HWSZ + n0;
    #pragma unroll
    for (int i = 0; i < 12; ++i){
      int e = i * 256 + tid;          // 3072 = 192c x 16 groups
      int c = e >> 4, ns = (e & 15) * 8;
      int4 v = *(const int4*)(vp + (size_t)c * HWSZ + ns);
      int kb = c >> 5, kr = c & 31;
      int tile = (kr >> 2) & 1;
      int mr = ((kr >> 3) << 2) | (kr & 3);
      int ti = (kb * 8 + (ns >> 4)) * 2 + tile;
      *(int4*)(&lV[ti * 264 + mr * 16 + (ns & 15)]) = v;
    }
  }
  __syncthreads();
  int lane = tid & 63, wid = tid >> 6;
  int quad = lane >> 4, r = lane & 15;
  int wm = (wid >> 1) * 32, wn = (wid & 1) * 64;
  unsigned lvb = (unsigned)(uintptr_t)(&lV[0]) + 2u * (unsigned)(r + quad * 64)
               + (unsigned)((wn >> 4) * 2) * 528u;
  f32x4 acc[2][4] = {};
  #pragma unroll
  for (int kb = 0; kb < 6; ++kb){
    int k0 = kb * 32;
    s16x4 lo[4], hi[4];
    #pragma unroll
    for (int j = 0; j < 4; ++j){
      unsigned a = lvb + (unsigned)kb * 8448u + (unsigned)j * 1056u;
      asm volatile("ds_read_b64_tr_b16 %0, %1" : "=&v"(lo[j]) : "v"(a));
      asm volatile("ds_read_b64_tr_b16 %0, %1 offset:528" : "=&v"(hi[j]) : "v"(a));
    }
    bf16x8 af[2];
    #pragma unroll
    for (int i = 0; i < 2; ++i)
      af[i] = *(const bf16x8*)(&lA[(wm + i * 16 + r) * 200 + k0 + quad * 8]);
    asm volatile("s_waitcnt lgkmcnt(0)" ::: "memory");
    __builtin_amdgcn_sched_barrier(0);
    #pragma unroll
    for (int j = 0; j < 4; ++j){
      union { s16x8 s; bf16x8 b; } u;
      u.s = __builtin_shufflevector(lo[j], hi[j], 0, 1, 2, 3, 4, 5, 6, 7);
      #pragma unroll
      for (int i = 0; i < 2; ++i)
        acc[i][j] = __builtin_amdgcn_mfma_f32_16x16x32_bf16(af[i], u.b, acc[i][j], 0, 0, 0);
    }
  }
  size_t obase = (size_t)b * CCH * HWSZ;
  #pragma unroll
  for (int i = 0; i < 2; ++i){
    #pragma unroll
    for (int rg = 0; rg < 4; ++rg){
      int o = m0 + wm + i * 16 + quad * 4 + rg;
      size_t rowb = obase + (size_t)o * HWSZ;
      #pragma unroll
      for (int j = 0; j < 4; ++j){
        int n = n0 + wn + j * 16 + r;
        Out[rowb + n] = acc[i][j][rg] + resid[rowb + n];
      }
    }
  }
}

// ---------------------------------------------------------------------------
extern "C" void kernel_launch(void* const* d_in, const int* in_sizes, int n_in,
                              void* d_out, int out_size, void* d_ws, size_t ws_size,
                              hipStream_t stream)
{
  const float* xx     = (const float*)d_in[0];
  const float* q_in   = (const float*)d_in[1];
  const float* ln_w   = (const float*)d_in[2];
  const float* ln_b   = (const float*)d_in[3];
  const float* w_q    = (const float*)d_in[4];
  const float* w_k    = (const float*)d_in[5];
  const float* w_v    = (const float*)d_in[6];
  const float* wd_q   = (const float*)d_in[7];
  const float* wd_k   = (const float*)d_in[8];
  const float* wd_v   = (const float*)d_in[9];
  const float* w_proj = (const float*)d_in[10];
  const float* temp   = (const float*)d_in[11];

  const size_t SZ = (size_t)NB * CCH * HWSZ;
  u16* B1 = (u16*)d_ws;                          // v_conv -> v_dw (in-place)
  u16* B2 = B1 + SZ;                             // k_conv -> k_dw (in-place)
  u16* B3 = B2 + SZ;                             // q_conv -> q_dw (in-place)
  float* G     = (float*)(B3 + SZ);
  float* ssq_q = G + 32 * DHEAD * DHEAD;
  float* ssq_k = ssq_q + NB * CCH;
  u16* Mb      = (u16*)(ssq_k + NB * CCH);       // fused proj matrices
  u16* Wb      = Mb + (size_t)NB * CCH * CCH;    // packed bf16 W*gamma (q,k,v)
  float* Ad    = (float*)(Wb + 3 * CCH * CCH);   // a,d rows [3][2][192]

  hipMemsetAsync(G, 0, (size_t)(32 * DHEAD * DHEAD + 2 * NB * CCH) * sizeof(float), stream);

  // fold LN gamma/beta into weights + row sums
  k_wpack<<<3, 256, 0, stream>>>(w_q, w_k, w_v, ln_w, ln_b, Wb, Ad);
  // fused LN-folded conv GEMMs (z=0: xx->{k,v}; z=1: q_in->q)
  k_convf<<<dim3(256, NB, 2), 256, 0, stream>>>(
      xx, q_in, Wb, Ad, B2, B1, B3);
  // merged depthwise: q in B3, k in B2, v in B1 — all in-place
  k_dw3<<<dim3(NB * CCH, 3), 256, 0, stream>>>(wd_q, wd_k, wd_v,
                                               B3, B2, B1, ssq_q, ssq_k);
  k_gram<<<dim3(16, NHEAD, NB), 256, 0, stream>>>(B3, B2, G);
  // fold softmax+proj into per-batch 192x192 matrix M
  k_mk<<<dim3(NHEAD, NB), 256, 0, stream>>>(G, ssq_q, ssq_k, temp, w_proj, Mb);
  // out = M @ V + q_in  (single fused GEMM)
  k_gemmv<<<dim3(128, 3, NB), 256, 0, stream>>>(Mb, B1, (float*)d_out, q_in);
}

// Round 8
// 445.685 us; speedup vs baseline: 1.0828x; 1.0828x over previous
//
#include <hip/hip_runtime.h>
#include <hip/hip_bf16.h>
#include <stdint.h>

#define HWSZ 16384
#define CCH 192
#define NB 8
#define NHEAD 4
#define DHEAD 48

typedef unsigned short u16;
typedef __bf16 bf16x8 __attribute__((ext_vector_type(8)));
typedef float f32x4 __attribute__((ext_vector_type(4)));
typedef short s16x8 __attribute__((ext_vector_type(8)));
typedef short s16x4 __attribute__((ext_vector_type(4)));

__device__ __forceinline__ float b2f(u16 h){
  union { unsigned u; float f; } v; v.u = ((unsigned)h) << 16; return v.f;
}
__device__ __forceinline__ u16 f2b(float f){
  union { float f; unsigned u; } v; v.f = f;
  unsigned r = v.u + 0x7fffu + ((v.u >> 16) & 1u);
  return (u16)(r >> 16);
}

// ---------------------------------------------------------------------------
// K0: fold LN gamma into weights: W'[o,c] = bf16(W[o,c]*g[c]); row sums
// a[o] = sum_c b2f(W'), d[o] = sum_c W[o,c]*b[c] (f32).  ad: [3][2][192].
// ---------------------------------------------------------------------------
__global__ __launch_bounds__(256) void k_wpack(
    const float* __restrict__ wq, const float* __restrict__ wk,
    const float* __restrict__ wv,
    const float* __restrict__ lnw, const float* __restrict__ lnb,
    u16* __restrict__ o, float* __restrict__ ad)
{
  int m = blockIdx.x;
  const float* src = (m == 0) ? wq : (m == 1) ? wk : wv;
  u16* dst = o + (size_t)m * CCH * CCH;
  int t = threadIdx.x;
  if (t < CCH){
    const float* row = src + (size_t)t * CCH;
    float a = 0.f, d = 0.f;
    for (int c = 0; c < CCH; c += 4){
      float4 w = *(const float4*)(row + c);
      float4 g = *(const float4*)(lnw + c);
      float4 bb = *(const float4*)(lnb + c);
      u16 p0 = f2b(w.x * g.x), p1 = f2b(w.y * g.y);
      u16 p2 = f2b(w.z * g.z), p3 = f2b(w.w * g.w);
      a += b2f(p0) + b2f(p1) + b2f(p2) + b2f(p3);
      d += w.x * bb.x + w.y * bb.y + w.z * bb.z + w.w * bb.w;
      s16x4 pk;
      pk[0] = (short)p0; pk[1] = (short)p1; pk[2] = (short)p2; pk[3] = (short)p3;
      *(s16x4*)(dst + (size_t)t * CCH + c) = pk;
    }
    ad[(m * 2 + 0) * CCH + t] = a;
    ad[(m * 2 + 1) * CCH + t] = d;
  }
}

// ---------------------------------------------------------------------------
// KC v2: LN-folded conv1x1 GEMM, 256-px tiles (1KB read / 512B write bursts
// per 32KB-strided row) + SWAPPED-operand MFMA so each lane holds 4
// consecutive px -> s16x4 8B stores (12/thread vs 48 scalar).
// z=0: xx -> {k,v}; z=1: q_in -> q.  1 block/CU (119.5 KB LDS), 8 waves.
// ---------------------------------------------------------------------------
__global__ __launch_bounds__(512, 2) void k_convf2(
    const float* __restrict__ xx, const float* __restrict__ q_in,
    const u16* __restrict__ Wb, const float* __restrict__ ad,
    u16* __restrict__ Ok, u16* __restrict__ Ov, u16* __restrict__ Oq)
{
  __shared__ u16 lnT[6 * 16 * 2 * 264];   // 101376 B subtiled bf16 [kb][g16][tile][264]
  __shared__ float2 redf[8][256];         // 16 KB wave partials {s,ss} per px
  __shared__ float mu_s[256];             // 1 KB
  __shared__ float rs_s[256];             // 1 KB
  int tid = threadIdx.x;
  int b = blockIdx.y, z = blockIdx.z;
  int p0 = blockIdx.x * 256;
  int lane = tid & 63, w = tid >> 6;
  int grp = tid & 31;        // 8-px group: px [grp*8, grp*8+8)
  int cr  = tid >> 5;        // 0..15 channel residue

  const float* xb = (z ? q_in : xx) + (size_t)b * CCH * HWSZ + p0 + grp * 8;

  // Phase A: stage raw x as bf16 (subtiled) + exact f32 per-px partial stats.
  float s[8] = {}, ss[8] = {};
  #pragma unroll
  for (int pass = 0; pass < 2; ++pass){
    float4 v[12];
    #pragma unroll
    for (int ii = 0; ii < 6; ++ii){
      int c = (pass * 6 + ii) * 16 + cr;
      v[2*ii]   = *(const float4*)(xb + (size_t)c * HWSZ);
      v[2*ii+1] = *(const float4*)(xb + (size_t)c * HWSZ + 4);
    }
    #pragma unroll
    for (int ii = 0; ii < 6; ++ii){
      int c = (pass * 6 + ii) * 16 + cr;
      float e0 = v[2*ii].x,   e1 = v[2*ii].y,   e2 = v[2*ii].z,   e3 = v[2*ii].w;
      float e4 = v[2*ii+1].x, e5 = v[2*ii+1].y, e6 = v[2*ii+1].z, e7 = v[2*ii+1].w;
      s[0]+=e0; ss[0]+=e0*e0; s[1]+=e1; ss[1]+=e1*e1;
      s[2]+=e2; ss[2]+=e2*e2; s[3]+=e3; ss[3]+=e3*e3;
      s[4]+=e4; ss[4]+=e4*e4; s[5]+=e5; ss[5]+=e5*e5;
      s[6]+=e6; ss[6]+=e6*e6; s[7]+=e7; ss[7]+=e7*e7;
      s16x8 pk;
      pk[0]=(short)f2b(e0); pk[1]=(short)f2b(e1); pk[2]=(short)f2b(e2); pk[3]=(short)f2b(e3);
      pk[4]=(short)f2b(e4); pk[5]=(short)f2b(e5); pk[6]=(short)f2b(e6); pk[7]=(short)f2b(e7);
      int kb = c >> 5, kr = c & 31;
      int tile = (kr >> 2) & 1;
      int mr   = ((kr >> 3) << 2) | (kr & 3);
      int ti   = (kb * 16 + (grp >> 1)) * 2 + tile;
      *(s16x8*)(&lnT[ti * 264 + mr * 16 + (grp & 1) * 8]) = pk;
    }
  }
  // reduce the cr-partner (lane^32), then wave partials -> LDS
  #pragma unroll
  for (int j = 0; j < 8; ++j){
    s[j]  += __shfl_xor(s[j],  32);
    ss[j] += __shfl_xor(ss[j], 32);
  }
  if (lane < 32){
    #pragma unroll
    for (int j = 0; j < 8; ++j)
      redf[w][grp * 8 + j] = make_float2(s[j], ss[j]);
  }
  __syncthreads();
  if (tid < 256){
    float sa = 0.f, qa = 0.f;
    #pragma unroll
    for (int ww = 0; ww < 8; ++ww){
      float2 t = redf[ww][tid];
      sa += t.x; qa += t.y;
    }
    float mu = sa * (1.f / CCH);
    float var = qa * (1.f / CCH) - mu * mu;
    mu_s[tid] = mu;
    rs_s[tid] = rsqrtf(var + 1e-5f);
  }
  __syncthreads();

  // Phase B: GEMM (swapped operands -> transposed tile, px contiguous per lane)
  int quad = lane >> 4, r = lane & 15;
  int wm = (w & 3) * 48;
  int mi, nh0, nhn;
  if (z == 0){ mi = (w >> 2) + 1; nh0 = 0; nhn = 4; }   // mats 1=k, 2=v
  else       { mi = 0; nh0 = (w >> 2) * 2; nhn = 2; }   // mat 0=q, split px
  const u16* A0 = Wb + (size_t)mi * CCH * CCH + (size_t)wm * CCH;
  const float* aA = ad + (mi * 2 + 0) * CCH;
  const float* dA = ad + (mi * 2 + 1) * CCH;
  u16* O = z ? Oq : ((w >> 2) ? Ov : Ok);
  size_t ob = (size_t)b * CCH * HWSZ;
  unsigned lvb0 = (unsigned)(uintptr_t)(&lnT[0]) + 2u * (unsigned)(r + quad * 64);

  float a_o[3], d_o[3];
  #pragma unroll
  for (int i = 0; i < 3; ++i){
    a_o[i] = aA[wm + i * 16 + r];
    d_o[i] = dA[wm + i * 16 + r];
  }

  for (int hh = 0; hh < nhn; ++hh){
    int nh = nh0 + hh;
    f32x4 acc[3][4] = {};
    bf16x8 aC[3], aN[3];
    #pragma unroll
    for (int i = 0; i < 3; ++i)
      aC[i] = *(const bf16x8*)(A0 + (size_t)(i * 16 + r) * CCH + quad * 8);
    #pragma unroll
    for (int kb = 0; kb < 6; ++kb){
      s16x4 lo[4], hi[4];
      #pragma unroll
      for (int j = 0; j < 4; ++j){
        unsigned a = lvb0 + (unsigned)(kb * 16896 + (nh * 4 + j) * 1056);
        asm volatile("ds_read_b64_tr_b16 %0, %1" : "=&v"(lo[j]) : "v"(a));
        asm volatile("ds_read_b64_tr_b16 %0, %1 offset:528" : "=&v"(hi[j]) : "v"(a));
      }
      if (kb < 5){
        #pragma unroll
        for (int i = 0; i < 3; ++i)
          aN[i] = *(const bf16x8*)(A0 + (size_t)(i * 16 + r) * CCH + (kb + 1) * 32 + quad * 8);
      }
      asm volatile("s_waitcnt lgkmcnt(0)" ::: "memory");
      __builtin_amdgcn_sched_barrier(0);
      #pragma unroll
      for (int j = 0; j < 4; ++j){
        union { s16x8 s; bf16x8 b; } u;
        u.s = __builtin_shufflevector(lo[j], hi[j], 0, 1, 2, 3, 4, 5, 6, 7);
        #pragma unroll
        for (int i = 0; i < 3; ++i)
          acc[i][j] = __builtin_amdgcn_mfma_f32_16x16x32_bf16(u.b, aC[i], acc[i][j], 0, 0, 0);
      }
      #pragma unroll
      for (int i = 0; i < 3; ++i) aC[i] = aN[i];
    }
    // Epilogue: lane holds px = nh*64 + j*16 + quad*4 + {0..3} for o = wm+i*16+r
    #pragma unroll
    for (int j = 0; j < 4; ++j){
      int pxb = nh * 64 + j * 16 + quad * 4;
      f32x4 mu4 = *(const f32x4*)(&mu_s[pxb]);
      f32x4 rs4 = *(const f32x4*)(&rs_s[pxb]);
      #pragma unroll
      for (int i = 0; i < 3; ++i){
        s16x4 pk;
        #pragma unroll
        for (int rg = 0; rg < 4; ++rg){
          float val = rs4[rg] * (acc[i][j][rg] - mu4[rg] * a_o[i]) + d_o[i];
          pk[rg] = (short)f2b(val);
        }
        int o = wm + i * 16 + r;
        *(s16x4*)(&O[ob + (size_t)o * HWSZ + p0 + pxb]) = pk;
      }
    }
  }
}

// ---------------------------------------------------------------------------
// K3: depthwise 3x3, register-rolling (no LDS). Thread = 8x8 px patch;
// 10 row loads up front (ILP), one __syncthreads (vmcnt drain) for in-place
// safety, halo via __shfl.
// ---------------------------------------------------------------------------
__global__ __launch_bounds__(256) void k_dw3(
    const float* __restrict__ wq, const float* __restrict__ wk,
    const float* __restrict__ wv,
    u16* __restrict__ bq, u16* __restrict__ bk, u16* __restrict__ bv,
    float* __restrict__ ssq_q, float* __restrict__ ssq_k)
{
  int tid = threadIdx.x;
  int bc  = blockIdx.x;                 // b*192 + c
  int z   = blockIdx.y;                 // 0=q 1=k 2=v
  int c   = bc % CCH;
  const float* wd = (z == 0) ? wq : (z == 1) ? wk : wv;
  u16* buf = (z == 0) ? bq : (z == 1) ? bk : bv;
  float w[9];
  #pragma unroll
  for (int t = 0; t < 9; ++t) w[t] = wd[c * 9 + t];
  u16* p = buf + (size_t)bc * HWSZ;

  int xseg = tid & 15, ygrp = tid >> 4;
  int x0 = xseg * 8, y0 = ygrp * 8;

  s16x8 zz = {0,0,0,0,0,0,0,0};
  s16x8 raw[10];
  #pragma unroll
  for (int rr = 0; rr < 10; ++rr){
    int yy = y0 - 1 + rr;
    raw[rr] = (yy >= 0 && yy < 128) ? *(const s16x8*)(p + yy * 128 + x0) : zz;
  }
  __syncthreads();

  float cf[10][8];
  float lf[10], rgt[10];
  #pragma unroll
  for (int rr = 0; rr < 10; ++rr){
    #pragma unroll
    for (int j = 0; j < 8; ++j) cf[rr][j] = b2f((u16)raw[rr][j]);
    float l  = __shfl_up(cf[rr][7], 1);
    float rr_ = __shfl_down(cf[rr][0], 1);
    lf[rr]  = (xseg > 0)  ? l   : 0.f;
    rgt[rr] = (xseg < 15) ? rr_ : 0.f;
  }

  float ss = 0.f;
  #pragma unroll
  for (int k = 0; k < 8; ++k){
    float acc[8] = {0.f,0.f,0.f,0.f,0.f,0.f,0.f,0.f};
    #pragma unroll
    for (int dy = 0; dy < 3; ++dy){
      int rr = k + dy;
      float wl = w[dy * 3], wc = w[dy * 3 + 1], wr = w[dy * 3 + 2];
      acc[0] += wl * lf[rr] + wc * cf[rr][0] + wr * cf[rr][1];
      #pragma unroll
      for (int j = 1; j < 7; ++j)
        acc[j] += wl * cf[rr][j - 1] + wc * cf[rr][j] + wr * cf[rr][j + 1];
      acc[7] += wl * cf[rr][6] + wc * cf[rr][7] + wr * rgt[rr];
    }
    s16x8 pk;
    #pragma unroll
    for (int j = 0; j < 8; ++j){
      pk[j] = (short)f2b(acc[j]);
      ss += acc[j] * acc[j];
    }
    *(s16x8*)(p + (y0 + k) * 128 + x0) = pk;
  }

  if (z < 2){
    #pragma unroll
    for (int m = 32; m > 0; m >>= 1) ss += __shfl_xor(ss, m);
    if ((tid & 63) == 0) atomicAdd(&((z == 0) ? ssq_q : ssq_k)[bc], ss);
  }
}

// ---------------------------------------------------------------------------
// K4: raw gram G[b][h][c][d] += sum_n q[c,n]*k[d,n], split-K (16 chunks),
// MFMA fragments straight from global; 4-wave LDS reduce then atomicAdd.
// ---------------------------------------------------------------------------
__global__ void k_gram(const u16* __restrict__ q, const u16* __restrict__ k,
                       float* __restrict__ G)
{
  __shared__ float gs[4 * 48 * 49];     // padded rows (49) to spread banks
  int tid = threadIdx.x;
  int chunk = blockIdx.x;
  int h = blockIdx.y, b = blockIdx.z;
  int lane = tid & 63, w = tid >> 6;
  int quad = lane >> 4, r = lane & 15;
  int nb = chunk * 1024 + w * 256;
  const u16* qb = q + ((size_t)b * CCH + h * DHEAD) * HWSZ;
  const u16* kb = k + ((size_t)b * CCH + h * DHEAD) * HWSZ;
  f32x4 acc[3][3] = {};
  for (int s = 0; s < 8; ++s){
    int kk = nb + s * 32 + quad * 8;
    bf16x8 af[3], bfr[3];
    #pragma unroll
    for (int i = 0; i < 3; ++i){
      af[i]  = *(const bf16x8*)(qb + (size_t)(i * 16 + r) * HWSZ + kk);
      bfr[i] = *(const bf16x8*)(kb + (size_t)(i * 16 + r) * HWSZ + kk);
    }
    #pragma unroll
    for (int i = 0; i < 3; ++i)
      #pragma unroll
      for (int j = 0; j < 3; ++j)
        acc[i][j] = __builtin_amdgcn_mfma_f32_16x16x32_bf16(af[i], bfr[j], acc[i][j], 0, 0, 0);
  }
  float* gw = gs + w * (48 * 49);
  #pragma unroll
  for (int i = 0; i < 3; ++i)
    #pragma unroll
    for (int j = 0; j < 3; ++j)
      #pragma unroll
      for (int rg = 0; rg < 4; ++rg){
        int row = i * 16 + quad * 4 + rg;
        int col = j * 16 + r;
        gw[row * 49 + col] = acc[i][j][rg];
      }
  __syncthreads();
  float* gb = G + (size_t)(b * NHEAD + h) * (DHEAD * DHEAD);
  #pragma unroll
  for (int t = 0; t < 9; ++t){
    int e = t * 256 + tid;              // 0..2303
    int row = e / 48, col = e - row * 48;
    int o = row * 49 + col;
    float s = gs[o] + gs[48 * 49 + o] + gs[2 * 48 * 49 + o] + gs[3 * 48 * 49 + o];
    atomicAdd(&gb[e], s);
  }
}

// ---------------------------------------------------------------------------
// K5: per (b,h) build M-slice = Wp[:, h*48:+48] @ P_h  (192x48, bf16)
// where P_h = softmax(G * rq*rk*temp). M is the fused (proj @ blockdiag(P)).
// ---------------------------------------------------------------------------
__global__ __launch_bounds__(256) void k_mk(
    const float* __restrict__ G, const float* __restrict__ ssq_q,
    const float* __restrict__ ssq_k, const float* __restrict__ temp,
    const float* __restrict__ wp, u16* __restrict__ Mout)
{
  __shared__ u16 Pt[48 * 72];     // P^T rows d, cols c (pad 48->72, zeros)
  __shared__ u16 wA[192 * 72];    // Wp head-slice rows o, cols c (pad zeros)
  __shared__ float rks[48];
  int tid = threadIdx.x;
  int h = blockIdx.x, b = blockIdx.y;
  {
    s16x8 z = {};
    #pragma unroll
    for (int i = 0; i < 2; ++i){
      int idx = (i * 256 + tid) * 8;
      if (idx < 48 * 72) *(s16x8*)(&Pt[idx]) = z;
    }
    #pragma unroll
    for (int i = 0; i < 7; ++i){
      int idx = (i * 256 + tid) * 8;
      if (idx < 192 * 72) *(s16x8*)(&wA[idx]) = z;
    }
  }
  if (tid < DHEAD)
    rks[tid] = 1.f / fmaxf(sqrtf(ssq_k[b * CCH + h * DHEAD + tid]), 1e-12f);
  __syncthreads();
  if (tid < DHEAD){
    float rq = temp[h] / fmaxf(sqrtf(ssq_q[b * CCH + h * DHEAD + tid]), 1e-12f);
    const float* gr = G + (size_t)(b * NHEAD + h) * (DHEAD * DHEAD) + tid * DHEAD;
    float a[DHEAD];
    float mx = -1e30f;
    #pragma unroll
    for (int d = 0; d < DHEAD; ++d){
      a[d] = gr[d] * rq * rks[d];
      mx = fmaxf(mx, a[d]);
    }
    float sum = 0.f;
    #pragma unroll
    for (int d = 0; d < DHEAD; ++d){ a[d] = __expf(a[d] - mx); sum += a[d]; }
    float inv = 1.f / sum;
    #pragma unroll
    for (int d = 0; d < DHEAD; ++d) Pt[d * 72 + tid] = f2b(a[d] * inv);
  }
  {
    const float* wb = wp + h * DHEAD;
    #pragma unroll
    for (int i = 0; i < 9; ++i){
      int e = (i * 256 + tid) * 4;       // 9216 = 192*48
      int row = e / DHEAD, col = e - row * DHEAD;
      float4 v = *(const float4*)(wb + (size_t)row * CCH + col);
      s16x4 pk;
      pk[0] = (short)f2b(v.x); pk[1] = (short)f2b(v.y);
      pk[2] = (short)f2b(v.z); pk[3] = (short)f2b(v.w);
      *(s16x4*)(&wA[row * 72 + col]) = pk;
    }
  }
  __syncthreads();
  int lane = tid & 63, wid = tid >> 6;
  int quad = lane >> 4, r = lane & 15;
  int wm = wid * 48;
  f32x4 acc[3][3] = {};
  #pragma unroll
  for (int ks = 0; ks < 2; ++ks){
    int k0 = ks * 32;
    bf16x8 af[3], bf[3];
    #pragma unroll
    for (int i = 0; i < 3; ++i)
      af[i] = *(const bf16x8*)(&wA[(wm + i * 16 + r) * 72 + k0 + quad * 8]);
    #pragma unroll
    for (int j = 0; j < 3; ++j)
      bf[j] = *(const bf16x8*)(&Pt[(j * 16 + r) * 72 + k0 + quad * 8]);
    #pragma unroll
    for (int i = 0; i < 3; ++i)
      #pragma unroll
      for (int j = 0; j < 3; ++j)
        acc[i][j] = __builtin_amdgcn_mfma_f32_16x16x32_bf16(af[i], bf[j], acc[i][j], 0, 0, 0);
  }
  u16* mb = Mout + (size_t)b * (CCH * CCH) + h * DHEAD;
  #pragma unroll
  for (int i = 0; i < 3; ++i)
    #pragma unroll
    for (int j = 0; j < 3; ++j)
      #pragma unroll
      for (int rg = 0; rg < 4; ++rg){
        int o = wm + i * 16 + quad * 4 + rg;
        int d = j * 16 + r;
        mb[(size_t)o * CCH + d] = f2b(acc[i][j][rg]);
      }
}

// ---------------------------------------------------------------------------
// K6: fused attention+proj GEMM  Out[b][o][n] = sum_c M[b][o][c]*V[b][c][n]
// + resid.  B-fragments via ds_read_b64_tr_b16 from 16x16-subtiled LDS.
// ---------------------------------------------------------------------------
__global__ __launch_bounds__(256) void k_gemmv(
    const u16* __restrict__ M, const u16* __restrict__ V,
    float* __restrict__ Out, const float* __restrict__ resid)
{
  __shared__ u16 lA[64 * 200];     // M slice rows
  __shared__ u16 lV[96 * 264];     // 6kb x 8nb x 2 tiles of 16x16 (+8 pad)
  int tid = threadIdx.x;
  int n0 = blockIdx.x * 128;
  int m0 = blockIdx.y * 64;
  int b  = blockIdx.z;
  {
    const u16* ap = M + (size_t)b * (CCH * CCH) + m0 * CCH;
    #pragma unroll
    for (int i = 0; i < 6; ++i){
      int off = (i * 256 + tid) * 8;
      int row = off / CCH, col = off - row * CCH;
      *(int4*)(&lA[row * 200 + col]) = *(const int4*)(ap + off);
    }
  }
  {
    const u16* vp = V + (size_t)b * CCH * HWSZ + n0;
    #pragma unroll
    for (int i = 0; i < 12; ++i){
      int e = i * 256 + tid;          // 3072 = 192c x 16 groups
      int c = e >> 4, ns = (e & 15) * 8;
      int4 v = *(const int4*)(vp + (size_t)c * HWSZ + ns);
      int kb = c >> 5, kr = c & 31;
      int tile = (kr >> 2) & 1;
      int mr = ((kr >> 3) << 2) | (kr & 3);
      int ti = (kb * 8 + (ns >> 4)) * 2 + tile;
      *(int4*)(&lV[ti * 264 + mr * 16 + (ns & 15)]) = v;
    }
  }
  __syncthreads();
  int lane = tid & 63, wid = tid >> 6;
  int quad = lane >> 4, r = lane & 15;
  int wm = (wid >> 1) * 32, wn = (wid & 1) * 64;
  unsigned lvb = (unsigned)(uintptr_t)(&lV[0]) + 2u * (unsigned)(r + quad * 64)
               + (unsigned)((wn >> 4) * 2) * 528u;
  f32x4 acc[2][4] = {};
  #pragma unroll
  for (int kb = 0; kb < 6; ++kb){
    int k0 = kb * 32;
    s16x4 lo[4], hi[4];
    #pragma unroll
    for (int j = 0; j < 4; ++j){
      unsigned a = lvb + (unsigned)kb * 8448u + (unsigned)j * 1056u;
      asm volatile("ds_read_b64_tr_b16 %0, %1" : "=&v"(lo[j]) : "v"(a));
      asm volatile("ds_read_b64_tr_b16 %0, %1 offset:528" : "=&v"(hi[j]) : "v"(a));
    }
    bf16x8 af[2];
    #pragma unroll
    for (int i = 0; i < 2; ++i)
      af[i] = *(const bf16x8*)(&lA[(wm + i * 16 + r) * 200 + k0 + quad * 8]);
    asm volatile("s_waitcnt lgkmcnt(0)" ::: "memory");
    __builtin_amdgcn_sched_barrier(0);
    #pragma unroll
    for (int j = 0; j < 4; ++j){
      union { s16x8 s; bf16x8 b; } u;
      u.s = __builtin_shufflevector(lo[j], hi[j], 0, 1, 2, 3, 4, 5, 6, 7);
      #pragma unroll
      for (int i = 0; i < 2; ++i)
        acc[i][j] = __builtin_amdgcn_mfma_f32_16x16x32_bf16(af[i], u.b, acc[i][j], 0, 0, 0);
    }
  }
  size_t obase = (size_t)b * CCH * HWSZ;
  #pragma unroll
  for (int i = 0; i < 2; ++i){
    #pragma unroll
    for (int rg = 0; rg < 4; ++rg){
      int o = m0 + wm + i * 16 + quad * 4 + rg;
      size_t rowb = obase + (size_t)o * HWSZ;
      #pragma unroll
      for (int j = 0; j < 4; ++j){
        int n = n0 + wn + j * 16 + r;
        Out[rowb + n] = acc[i][j][rg] + resid[rowb + n];
      }
    }
  }
}

// ---------------------------------------------------------------------------
extern "C" void kernel_launch(void* const* d_in, const int* in_sizes, int n_in,
                              void* d_out, int out_size, void* d_ws, size_t ws_size,
                              hipStream_t stream)
{
  const float* xx     = (const float*)d_in[0];
  const float* q_in   = (const float*)d_in[1];
  const float* ln_w   = (const float*)d_in[2];
  const float* ln_b   = (const float*)d_in[3];
  const float* w_q    = (const float*)d_in[4];
  const float* w_k    = (const float*)d_in[5];
  const float* w_v    = (const float*)d_in[6];
  const float* wd_q   = (const float*)d_in[7];
  const float* wd_k   = (const float*)d_in[8];
  const float* wd_v   = (const float*)d_in[9];
  const float* w_proj = (const float*)d_in[10];
  const float* temp   = (const float*)d_in[11];

  const size_t SZ = (size_t)NB * CCH * HWSZ;
  u16* B1 = (u16*)d_ws;                          // v_conv -> v_dw (in-place)
  u16* B2 = B1 + SZ;                             // k_conv -> k_dw (in-place)
  u16* B3 = B2 + SZ;                             // q_conv -> q_dw (in-place)
  float* G     = (float*)(B3 + SZ);
  float* ssq_q = G + 32 * DHEAD * DHEAD;
  float* ssq_k = ssq_q + NB * CCH;
  u16* Mb      = (u16*)(ssq_k + NB * CCH);       // fused proj matrices
  u16* Wb      = Mb + (size_t)NB * CCH * CCH;    // packed bf16 W*gamma (q,k,v)
  float* Ad    = (float*)(Wb + 3 * CCH * CCH);   // a,d rows [3][2][192]

  hipMemsetAsync(G, 0, (size_t)(32 * DHEAD * DHEAD + 2 * NB * CCH) * sizeof(float), stream);

  // fold LN gamma/beta into weights + row sums
  k_wpack<<<3, 256, 0, stream>>>(w_q, w_k, w_v, ln_w, ln_b, Wb, Ad);
  // fused LN-folded conv GEMMs, 256-px tiles (z=0: xx->{k,v}; z=1: q_in->q)
  k_convf2<<<dim3(64, NB, 2), 512, 0, stream>>>(
      xx, q_in, Wb, Ad, B2, B1, B3);
  // merged depthwise: q in B3, k in B2, v in B1 — all in-place
  k_dw3<<<dim3(NB * CCH, 3), 256, 0, stream>>>(wd_q, wd_k, wd_v,
                                               B3, B2, B1, ssq_q, ssq_k);
  k_gram<<<dim3(16, NHEAD, NB), 256, 0, stream>>>(B3, B2, G);
  // fold softmax+proj into per-batch 192x192 matrix M
  k_mk<<<dim3(NHEAD, NB), 256, 0, stream>>>(G, ssq_q, ssq_k, temp, w_proj, Mb);
  // out = M @ V + q_in  (single fused GEMM)
  k_gemmv<<<dim3(128, 3, NB), 256, 0, stream>>>(Mb, B1, (float*)d_out, q_in);
}